// Round 4
// baseline (261.595 us; speedup 1.0000x reference)
//
#include <hip/hip_runtime.h>
#include <math.h>

#define NA 3
#define NM 32
#define NC 80
#define STRIDE_PX 8.0f
#define THRESH 0.05f
#define NB 16
#define NH 80
#define NW 80
#define NHW (NH * NW)                 // 6400
#define CH (NA * (5 + NC) + NA * NM)  // 351
#define BOXCH (NA * (5 + NC))         // 255
#define TOTAL (NB * NA * NHW)         // 307200
#define BLK 256
#define NBLK (TOTAL / BLK)            // 1200
#define ROWSZ 39                      // 7 + NM output row
#define HDR 8                         // ws header floats per kept row (two float4)

__device__ __forceinline__ int wave_sum64(int v) {
#pragma unroll
  for (int s = 32; s > 0; s >>= 1) v += __shfl_xor(v, s, 64);
  return v;
}

// ---- Kernel A: decode + chunked softmax + score; write 8-float header per keep ----
// Masks are NOT read here; emit gathers them straight from `in` (same cacheline
// touch pattern, but saves the 2x12.8 MB ws round-trip of mask payload).
__global__ __launch_bounds__(BLK, 4) void decode_kernel(
    const float* __restrict__ in, const float* __restrict__ anchors,
    float* __restrict__ wshdr, int* __restrict__ counts) {
  int g = blockIdx.x * BLK + threadIdx.x;
  int p = g % NHW;
  int a = (g / NHW) % NA;
  int b = g / (NA * NHW);

  const float* base = in + ((size_t)b * CH + (size_t)a * (5 + NC)) * NHW + p;

  float tx = base[0];
  float ty = base[(size_t)1 * NHW];
  float tw = base[(size_t)2 * NHW];
  float th = base[(size_t)3 * NHW];
  float tobj = base[(size_t)4 * NHW];

  // chunked online softmax (10 x 8): tree max/argmax, independent exps per chunk
  float m = -INFINITY, s = 0.f;
  int idx = 0;
#pragma unroll
  for (int c = 0; c < NC; c += 8) {
    float x[8];
#pragma unroll
    for (int j = 0; j < 8; ++j) x[j] = base[(size_t)(5 + c + j) * NHW];

    float m4[4]; int i4[4];
#pragma unroll
    for (int k = 0; k < 4; ++k) {
      bool gt = x[2 * k + 1] > x[2 * k];
      m4[k] = gt ? x[2 * k + 1] : x[2 * k];
      i4[k] = gt ? (2 * k + 1) : (2 * k);
    }
    float m2[2]; int i2[2];
#pragma unroll
    for (int k = 0; k < 2; ++k) {
      bool gt = m4[2 * k + 1] > m4[2 * k];
      m2[k] = gt ? m4[2 * k + 1] : m4[2 * k];
      i2[k] = gt ? i4[2 * k + 1] : i4[2 * k];
    }
    bool gtc = m2[1] > m2[0];
    float mc = gtc ? m2[1] : m2[0];
    int ic = (gtc ? i2[1] : i2[0]) + c;

    float e0 = __expf(x[0] - mc), e1 = __expf(x[1] - mc);
    float e2 = __expf(x[2] - mc), e3 = __expf(x[3] - mc);
    float e4 = __expf(x[4] - mc), e5 = __expf(x[5] - mc);
    float e6 = __expf(x[6] - mc), e7 = __expf(x[7] - mc);
    float sc = ((e0 + e1) + (e2 + e3)) + ((e4 + e5) + (e6 + e7));

    float mn = fmaxf(m, mc);
    s = s * __expf(m - mn) + sc * __expf(mc - mn);
    idx = (mc > m) ? ic : idx;  // strict >: first occurrence wins across chunks
    m = mn;
  }

  float score = (1.0f / s) * (1.0f / (1.0f + __expf(-tobj)));

  float amax = fmaxf(fmaxf(fmaxf(anchors[0], anchors[1]), fmaxf(anchors[2], anchors[3])),
                     fmaxf(anchors[4], anchors[5]));
  float max_value = floorf(logf(1e35f / amax / STRIDE_PX));
  float aw = anchors[a * 2 + 0];
  float ah = anchors[a * 2 + 1];

  float xs = 1.0f / (1.0f + __expf(-tx)) + (float)(p % NW);
  float ys = 1.0f / (1.0f + __expf(-ty)) + (float)(p / NW);
  float w = __expf(fminf(tw, max_value)) * aw;
  float h = __expf(fminf(th, max_value)) * ah;

  // block-local rank (thread order == global (b,a,p) order)
  bool keep = score > THRESH;
  unsigned long long ball = __ballot(keep);
  int lane = threadIdx.x & 63;
  int wv = threadIdx.x >> 6;
  int lower = __popcll(ball & ((1ull << lane) - 1ull));
  __shared__ int wc[BLK / 64];
  if (lane == 0) wc[wv] = __popcll(ball);
  __syncthreads();
  int pre = 0;
#pragma unroll
  for (int i = 0; i < BLK / 64; ++i)
    if (i < wv) pre += wc[i];

  if (keep) {
    int lrank = pre + lower;
    float4* o4 = reinterpret_cast<float4*>(
        wshdr + ((size_t)blockIdx.x * BLK + (size_t)lrank) * HDR);
    float4 v;
    v.x = (float)b; v.y = xs * STRIDE_PX; v.z = ys * STRIDE_PX; v.w = w * STRIDE_PX;
    o4[0] = v;
    v.x = h * STRIDE_PX; v.y = score; v.z = (float)idx; v.w = __int_as_float(g);
    o4[1] = v;
  }
  if (threadIdx.x == 0)
    counts[blockIdx.x] = wc[0] + wc[1] + wc[2] + wc[3];
}

// ---- Kernel B: redundant prefix over 1200 counts; one thread per kept row ----
// Header from ws (coalesced float4), masks gathered directly from `in`.
__global__ __launch_bounds__(BLK, 4) void emit_kernel(
    const float* __restrict__ in, const float* __restrict__ wshdr,
    const int* __restrict__ counts, float* __restrict__ out, int out_size) {
  int bid = blockIdx.x;
  int t = threadIdx.x;

  int partial = 0;
  for (int j = t; j < bid; j += BLK) partial += counts[j];
  partial = wave_sum64(partial);
  __shared__ int sh[BLK / 64];
  if ((t & 63) == 0) sh[t >> 6] = partial;
  __syncthreads();
  int off = sh[0] + sh[1] + sh[2] + sh[3];

  int cnt = counts[bid];
  if (t >= cnt) return;

  const float4* h4 = reinterpret_cast<const float4*>(
      wshdr + ((size_t)bid * BLK + (size_t)t) * HDR);
  float4 h0 = h4[0];
  float4 h1 = h4[1];
  int g = __float_as_int(h1.w);
  int p = g % NHW;
  int a = (g / NHW) % NA;
  int b = g / (NA * NHW);

  int dbase = (off + t) * ROWSZ;
#define ST(o, v)                       \
  do {                                 \
    int dd = dbase + (o);              \
    if (dd < out_size) out[dd] = (v);  \
  } while (0)

  ST(0, h0.x);  // b
  ST(1, h0.y);  // x
  ST(2, h0.z);  // y
  ST(3, h0.w);  // w
  ST(4, h1.x);  // h

  const float* mbase = in + ((size_t)b * CH + BOXCH + (size_t)a * NM) * NHW + p;
#pragma unroll
  for (int mm = 0; mm < NM; ++mm) ST(5 + mm, mbase[(size_t)mm * NHW]);

  ST(5 + NM, h1.y);  // score
  ST(6 + NM, h1.z);  // class idx
#undef ST
}

extern "C" void kernel_launch(void* const* d_in, const int* in_sizes, int n_in,
                              void* d_out, int out_size, void* d_ws, size_t ws_size,
                              hipStream_t stream) {
  const float* in = (const float*)d_in[0];
  const float* anchors = (const float*)d_in[1];

  float* wshdr = (float*)d_ws;  // NBLK * BLK * 8 floats (~9.8 MB)
  int* counts = (int*)((float*)d_ws + (size_t)NBLK * BLK * HDR);

  decode_kernel<<<NBLK, BLK, 0, stream>>>(in, anchors, wshdr, counts);
  emit_kernel<<<NBLK, BLK, 0, stream>>>(in, wshdr, counts, (float*)d_out, out_size);
}

// Round 5
// 226.377 us; speedup vs baseline: 1.1556x; 1.1556x over previous
//
#include <hip/hip_runtime.h>
#include <math.h>

#define NA 3
#define NM 32
#define NC 80
#define STRIDE_PX 8.0f
#define THRESH 0.05f
#define NB 16
#define NH 80
#define NW 80
#define NHW (NH * NW)                 // 6400
#define CH (NA * (5 + NC) + NA * NM)  // 351
#define BOXCH (NA * (5 + NC))         // 255
#define TOTAL (NB * NA * NHW)         // 307200
#define BLK 256
#define NBLK (TOTAL / BLK)            // 1200
#define ROWSZ 39                      // packed output row (7 + NM)
#define ROWPAD 40                     // padded ws row -> 160 B, float4-aligned
#define WS_ROW_STRIDE (BLK * ROWPAD)  // 10240 floats per block slab

__device__ __forceinline__ int wave_sum64(int v) {
#pragma unroll
  for (int s = 32; s > 0; s >>= 1) v += __shfl_xor(v, s, 64);
  return v;
}

// ---- Kernel A: decode + chunked-tree softmax + score; block-local compaction ----
// Chunked softmax (5 x 16): tree max (log-depth) + independent exps per chunk.
// Rows padded to 40 floats so each keep-lane emits 10 float4 stores (16B/lane).
__global__ __launch_bounds__(BLK, 6) void decode_kernel(
    const float* __restrict__ in, const float* __restrict__ anchors,
    float* __restrict__ wsrows, int* __restrict__ counts) {
  int g = blockIdx.x * BLK + threadIdx.x;
  int p = g % NHW;
  int a = (g / NHW) % NA;
  int b = g / (NA * NHW);

  const float* base = in + ((size_t)b * CH + (size_t)a * (5 + NC)) * NHW + p;

  float tx = base[0];
  float ty = base[(size_t)1 * NHW];
  float tw = base[(size_t)2 * NHW];
  float th = base[(size_t)3 * NHW];
  float tobj = base[(size_t)4 * NHW];

  float m = -INFINITY, s = 0.f;
  int idx = 0;
#pragma unroll
  for (int c = 0; c < NC; c += 16) {
    float x[16];
#pragma unroll
    for (int j = 0; j < 16; ++j) x[j] = base[(size_t)(5 + c + j) * NHW];

    // tree max + first-occurrence argmax (strict > prefers lower index on ties)
    float m8[8]; int i8[8];
#pragma unroll
    for (int k = 0; k < 8; ++k) {
      bool gt = x[2 * k + 1] > x[2 * k];
      m8[k] = gt ? x[2 * k + 1] : x[2 * k];
      i8[k] = gt ? (2 * k + 1) : (2 * k);
    }
    float m4[4]; int i4[4];
#pragma unroll
    for (int k = 0; k < 4; ++k) {
      bool gt = m8[2 * k + 1] > m8[2 * k];
      m4[k] = gt ? m8[2 * k + 1] : m8[2 * k];
      i4[k] = gt ? i8[2 * k + 1] : i8[2 * k];
    }
    float m2[2]; int i2[2];
#pragma unroll
    for (int k = 0; k < 2; ++k) {
      bool gt = m4[2 * k + 1] > m4[2 * k];
      m2[k] = gt ? m4[2 * k + 1] : m4[2 * k];
      i2[k] = gt ? i4[2 * k + 1] : i4[2 * k];
    }
    bool gtc = m2[1] > m2[0];
    float mc = gtc ? m2[1] : m2[0];
    int ic = (gtc ? i2[1] : i2[0]) + c;

    // 16 independent exps (pipeline-friendly), pairwise sum
    float e[16];
#pragma unroll
    for (int j = 0; j < 16; ++j) e[j] = __expf(x[j] - mc);
    float s8[8];
#pragma unroll
    for (int k = 0; k < 8; ++k) s8[k] = e[2 * k] + e[2 * k + 1];
    float s4[4];
#pragma unroll
    for (int k = 0; k < 4; ++k) s4[k] = s8[2 * k] + s8[2 * k + 1];
    float sc = (s4[0] + s4[1]) + (s4[2] + s4[3]);

    // serial merge: only 5 of these in the whole kernel
    float mn = fmaxf(m, mc);
    s = s * __expf(m - mn) + sc * __expf(mc - mn);
    idx = (mc > m) ? ic : idx;  // strict > keeps first occurrence across chunks
    m = mn;
  }

  float cls_max = 1.0f / s;
  float obj = 1.0f / (1.0f + __expf(-tobj));
  float score = cls_max * obj;

  float amax = fmaxf(fmaxf(fmaxf(anchors[0], anchors[1]), fmaxf(anchors[2], anchors[3])),
                     fmaxf(anchors[4], anchors[5]));
  float max_value = floorf(logf(1e35f / amax / STRIDE_PX));
  float aw = anchors[a * 2 + 0];
  float ah = anchors[a * 2 + 1];

  float xs = 1.0f / (1.0f + __expf(-tx)) + (float)(p % NW);
  float ys = 1.0f / (1.0f + __expf(-ty)) + (float)(p / NW);
  float w = __expf(fminf(tw, max_value)) * aw;
  float h = __expf(fminf(th, max_value)) * ah;

  // block-local rank (thread order == global (b,a,p) order)
  bool keep = score > THRESH;
  unsigned long long ball = __ballot(keep);
  int lane = threadIdx.x & 63;
  int wv = threadIdx.x >> 6;
  int lower = __popcll(ball & ((1ull << lane) - 1ull));
  __shared__ int wc[BLK / 64];
  if (lane == 0) wc[wv] = __popcll(ball);
  __syncthreads();
  int pre = 0;
#pragma unroll
  for (int i = 0; i < BLK / 64; ++i)
    if (i < wv) pre += wc[i];

  if (keep) {
    int lrank = pre + lower;
    float4* o4 = reinterpret_cast<float4*>(
        wsrows + (size_t)blockIdx.x * WS_ROW_STRIDE + (size_t)lrank * ROWPAD);
    const float* mbase = in + ((size_t)b * CH + BOXCH + (size_t)a * NM) * NHW + p;

    float4 v;
    v.x = (float)b; v.y = xs * STRIDE_PX; v.z = ys * STRIDE_PX; v.w = w * STRIDE_PX;
    o4[0] = v;
    v.x = h * STRIDE_PX; v.y = mbase[0]; v.z = mbase[(size_t)1 * NHW]; v.w = mbase[(size_t)2 * NHW];
    o4[1] = v;
#pragma unroll
    for (int gq = 2; gq <= 8; ++gq) {   // masks m3..m30 in groups of 4
      v.x = mbase[(size_t)(4 * gq - 5) * NHW];
      v.y = mbase[(size_t)(4 * gq - 4) * NHW];
      v.z = mbase[(size_t)(4 * gq - 3) * NHW];
      v.w = mbase[(size_t)(4 * gq - 2) * NHW];
      o4[gq] = v;
    }
    v.x = mbase[(size_t)31 * NHW]; v.y = score; v.z = (float)idx; v.w = 0.f;
    o4[9] = v;
  }
  if (threadIdx.x == 0)
    counts[blockIdx.x] = wc[0] + wc[1] + wc[2] + wc[3];
}

// ---- Kernel B: per-block redundant prefix over 1200 counts + packed linear copy ----
__global__ __launch_bounds__(BLK, 8) void emit_kernel(
    const float* __restrict__ wsrows, const int* __restrict__ counts,
    float* __restrict__ out, int out_size) {
  int bid = blockIdx.x;
  int t = threadIdx.x;

  int partial = 0;
  for (int j = t; j < bid; j += BLK) partial += counts[j];
  partial = wave_sum64(partial);
  __shared__ int sh[BLK / 64];
  if ((t & 63) == 0) sh[t >> 6] = partial;
  __syncthreads();
  int off = sh[0] + sh[1] + sh[2] + sh[3];

  int cnt = counts[bid];
  int nelem = cnt * ROWSZ;
  const float* src = wsrows + (size_t)bid * WS_ROW_STRIDE;
  int dbase = off * ROWSZ;
  for (int e = t; e < nelem; e += BLK) {
    int row = (int)(((unsigned)e * 107547u) >> 22);  // e/39, exact for e < 144611
    int col = e - row * 39;
    int d = dbase + e;
    if (d < out_size) out[d] = src[row * ROWPAD + col];
  }
}

extern "C" void kernel_launch(void* const* d_in, const int* in_sizes, int n_in,
                              void* d_out, int out_size, void* d_ws, size_t ws_size,
                              hipStream_t stream) {
  const float* in = (const float*)d_in[0];
  const float* anchors = (const float*)d_in[1];

  float* wsrows = (float*)d_ws;  // NBLK * 10240 floats (~49 MB)
  int* counts = (int*)((float*)d_ws + (size_t)NBLK * WS_ROW_STRIDE);

  decode_kernel<<<NBLK, BLK, 0, stream>>>(in, anchors, wsrows, counts);
  emit_kernel<<<NBLK, BLK, 0, stream>>>(wsrows, counts, (float*)d_out, out_size);
}